// Round 4
// baseline (109.118 us; speedup 1.0000x reference)
//
#include <hip/hip_runtime.h>
#include <hip/hip_bf16.h>
#include <math.h>

#define B_ 4096
#define F_ 64
#define A_ 8
#define U_ 32

typedef float f32x4 __attribute__((ext_vector_type(4)));
typedef short bf16x8 __attribute__((ext_vector_type(8)));

// ws layout:
//   [0, 4 MB): frag blob, per (a,j) 8192 B, index (a*64+j):
//     [0,4096):  K B-frags, fragid = kc*2+ut, 64 lanes x 16 B:
//                bf16 K[f = kc*32 + q*8 + jj][u = ut*16 + c]
//     [4096,8192): W B-frags, fragid = ft:
//                bf16 exp(2*K[f = ft*16 + c][u = q*8 + jj])
//   [4 MB, 4 MB + 64 KB): Kd fp32 (bf16-rounded values): [a*64+j][32] = K[j,a][j][u]
#define KD_OFF (4ull << 20)

static __device__ __forceinline__ unsigned int pk_bf16(float lo, float hi) {
    union { __hip_bfloat162 h2; unsigned int u; } cv;
    cv.h2 = __float22bfloat162_rn(make_float2(lo, hi));
    return cv.u;
}
// round fp32 -> bf16 -> fp32 (match what the MFMA actually sees)
static __device__ __forceinline__ float rb(float f) {
    unsigned int u = __float_as_uint(f);
    u += 0x7FFFu + ((u >> 16) & 1u);
    return __uint_as_float(u & 0xFFFF0000u);
}

// ---------------- prep: one block per (a,j); stage 8 KB, emit frags + Kd ----------------
__global__ __launch_bounds__(256) void ife_prep(const float* __restrict__ kern,
                                                unsigned char* __restrict__ ws)
{
    const int bid = blockIdx.x;           // a*64 + j
    const int a = bid >> 6, j = bid & 63;
    const int t = threadIdx.x;
    __shared__ float st[64][36];          // [f][u], pitch 36 (16B-aligned float4 slots)

    const float* src = kern + ((size_t)j * A_ + a) * (F_ * U_);
    {
        const int f = t >> 2, u0 = (t & 3) * 8;
        *(float4*)&st[f][u0]     = *(const float4*)&src[f * U_ + u0];
        *(float4*)&st[f][u0 + 4] = *(const float4*)&src[f * U_ + u0 + 4];
    }
    __syncthreads();

    unsigned char* dst = ws + (size_t)bid * 8192;
    const int fragid = t >> 6, lane = t & 63, q = lane >> 4, c = lane & 15;

    // K B-frag (fragid = kc*2 + ut)
    {
        const int kc = fragid >> 1, ut = fragid & 1;
        const int f0 = kc * 32 + q * 8, u = ut * 16 + c;
        unsigned int w[4];
        #pragma unroll
        for (int i = 0; i < 4; ++i)
            w[i] = pk_bf16(st[f0 + 2 * i][u], st[f0 + 2 * i + 1][u]);
        *(uint4*)(dst + fragid * 1024 + lane * 16) = make_uint4(w[0], w[1], w[2], w[3]);
    }
    // W B-frag (fragid = ft)
    {
        const int f = fragid * 16 + c, u0 = q * 8;
        const float4 wa = *(const float4*)&st[f][u0];
        const float4 wb = *(const float4*)&st[f][u0 + 4];
        unsigned int w[4];
        w[0] = pk_bf16(__expf(2.f * wa.x), __expf(2.f * wa.y));
        w[1] = pk_bf16(__expf(2.f * wa.z), __expf(2.f * wa.w));
        w[2] = pk_bf16(__expf(2.f * wb.x), __expf(2.f * wb.y));
        w[3] = pk_bf16(__expf(2.f * wb.z), __expf(2.f * wb.w));
        *(uint4*)(dst + 4096 + fragid * 1024 + lane * 16) = make_uint4(w[0], w[1], w[2], w[3]);
    }
    // Kd (bf16-rounded so the rank-1 correction exactly cancels the MFMA j-term)
    if (t < U_)
        ((float*)(ws + KD_OFF))[(size_t)bid * U_ + t] = rb(st[j][t]);
}

// ---------------- main: (a, 64-row tile); 8 waves, each wave = ALL 64 rows x 8 j's ----------
// R3 showed the kernel is L2-BW-bound: every wave re-read the 8 KB/j frag set for only 16
// output rows (1.07 GB L2 traffic ~ 24 TB/s). Here each wave computes 4 row-blocks (64 rows)
// per frag load -> 4x less frag traffic (268 MB). Per j: phase A (K-frags, 16 Z-MFMAs, exp,
// Pbuf writes x4 rb), ONE lgkmcnt drain, phase B (W-frags, perm, 20 PV-MFMAs, accumulate).
// K/W not co-resident -> peak VGPR ~150 under the (512,3) cap of 170 (R2 spill lesson:
// WRITE_SIZE is the tripwire). Partial S reduced across waves through LDS (Pbuf overlay).
__global__ __launch_bounds__(512, 3) void ife_main(const float* __restrict__ x,
                                                   const unsigned char* __restrict__ ws,
                                                   float* __restrict__ out)
{
    const int a = blockIdx.y, bt = blockIdx.x, t = threadIdx.x;
    const int wv = t >> 6, lane = t & 63, q = lane >> 4, c = lane & 15;

    __shared__ __align__(16) float Xf[64][66];         // bf16-rounded fp32 X tile (16.9 KB)
    __shared__ float Kd[64][32];                       // bf16-rounded K[j][j][u] (8 KB)
    __shared__ __align__(16) unsigned int Pbuf[8][4][16][20];  // per-wave, per-row-block E (40 KB)

    // X A-frags for ALL 4 row-blocks (m = c, k = kc*32 + q*8 + i), pure bf16
    bf16x8 Xh[4][2];
    #pragma unroll
    for (int rbk = 0; rbk < 4; ++rbk) {
        const float* xr = x + (size_t)(bt * 64 + rbk * 16 + c) * F_;
        #pragma unroll
        for (int kc = 0; kc < 2; ++kc) {
            const float4 va = *(const float4*)&xr[kc * 32 + q * 8];
            const float4 vb = *(const float4*)&xr[kc * 32 + q * 8 + 4];
            union { unsigned int u[4]; bf16x8 v; } H;
            H.u[0] = pk_bf16(va.x, va.y);
            H.u[1] = pk_bf16(va.z, va.w);
            H.u[2] = pk_bf16(vb.x, vb.y);
            H.u[3] = pk_bf16(vb.z, vb.w);
            Xh[rbk][kc] = H.v;
        }
    }
    // Xf (bf16-rounded values, fp32 storage, broadcast-friendly); 512 threads
    {
        const int row = t >> 3, cb = (t & 7) * 8;
        const float* xsrc = x + (size_t)(bt * 64 + row) * F_ + cb;
        const float4 v0 = *(const float4*)&xsrc[0];
        const float4 v1 = *(const float4*)&xsrc[4];
        Xf[row][cb + 0] = rb(v0.x); Xf[row][cb + 1] = rb(v0.y);
        Xf[row][cb + 2] = rb(v0.z); Xf[row][cb + 3] = rb(v0.w);
        Xf[row][cb + 4] = rb(v1.x); Xf[row][cb + 5] = rb(v1.y);
        Xf[row][cb + 6] = rb(v1.z); Xf[row][cb + 7] = rb(v1.w);
    }
    // Kd stage (contiguous 8 KB); 512 threads x 1 float4
    {
        const float* kd = (const float*)(ws + KD_OFF) + (size_t)a * 64 * U_;
        const int jj = t >> 3, u0 = (t & 7) * 4;
        *(float4*)&Kd[jj][u0] = *(const float4*)&kd[jj * U_ + u0];
    }
    __syncthreads();   // staging barrier

    const unsigned int psel = (q < 2) ? 0x05040100u : 0x07060302u;
    const unsigned char* fbase = ws + (size_t)a * 64 * 8192 + (size_t)lane * 16;

    union { unsigned int u[4]; bf16x8 v; } oc;
    oc.u[0] = 0x3F803F80u; oc.u[1] = 0x3F803F80u; oc.u[2] = 0x3F803F80u; oc.u[3] = 0x3F803F80u;
    const bf16x8 ONES = oc.v;
    const f32x4 vzero = (f32x4){0.f, 0.f, 0.f, 0.f};

    f32x4 S[4][4];
    #pragma unroll
    for (int rbk = 0; rbk < 4; ++rbk) {
        S[rbk][0] = vzero; S[rbk][1] = vzero; S[rbk][2] = vzero; S[rbk][3] = vzero;
    }

    // ---- j loop: this wave's 8 exclusion indices over all 64 rows ----
    #pragma unroll 1
    for (int jj = 0; jj < 8; ++jj) {
        const int j = (wv << 3) + jj;
        const unsigned char* p = fbase + (size_t)j * 8192;

        const float kd0 = Kd[j][c], kd1 = Kd[j][16 + c];

        // ---- phase A: K frags -> Z -> exp -> Pbuf (all 4 row-blocks) ----
        bf16x8 K[4];
        #pragma unroll
        for (int i = 0; i < 4; ++i) K[i] = *(const bf16x8*)(p + i * 1024);

        #pragma unroll
        for (int rbk = 0; rbk < 4; ++rbk) {
            f32x4 ZA = vzero, ZB = vzero;
            ZA = __builtin_amdgcn_mfma_f32_16x16x32_bf16(Xh[rbk][0], K[0], ZA, 0, 0, 0);
            ZA = __builtin_amdgcn_mfma_f32_16x16x32_bf16(Xh[rbk][1], K[2], ZA, 0, 0, 0);
            ZB = __builtin_amdgcn_mfma_f32_16x16x32_bf16(Xh[rbk][0], K[1], ZB, 0, 0, 0);
            ZB = __builtin_amdgcn_mfma_f32_16x16x32_bf16(Xh[rbk][1], K[3], ZB, 0, 0, 0);
            #pragma unroll
            for (int r = 0; r < 4; ++r) {
                const float xj = Xf[rbk * 16 + q * 4 + r][j];
                const float e0 = __expf(ZA[r] - xj * kd0);
                const float e1 = __expf(ZB[r] - xj * kd1);
                Pbuf[wv][rbk][q * 4 + r][c] = pk_bf16(e0, e1);
            }
        }

        // ---- phase B: W frags, ONE drain, transposed read + perm + PV (x4 row-blocks) ----
        bf16x8 W[4];
        #pragma unroll
        for (int i = 0; i < 4; ++i) W[i] = *(const bf16x8*)(p + 4096 + i * 1024);

        asm volatile("s_waitcnt lgkmcnt(0)" ::: "memory");  // all 16 Pbuf writes drained

        #pragma unroll
        for (int rbk = 0; rbk < 4; ++rbk) {
            const uint4 pa = *(const uint4*)&Pbuf[wv][rbk][c][(q & 1) * 8];
            const uint4 pb = *(const uint4*)&Pbuf[wv][rbk][c][(q & 1) * 8 + 4];
            union { unsigned int u[4]; bf16x8 v; } E;
            E.u[0] = __builtin_amdgcn_perm(pa.y, pa.x, psel);
            E.u[1] = __builtin_amdgcn_perm(pa.w, pa.z, psel);
            E.u[2] = __builtin_amdgcn_perm(pb.y, pb.x, psel);
            E.u[3] = __builtin_amdgcn_perm(pb.w, pb.z, psel);

            const f32x4 sv = __builtin_amdgcn_mfma_f32_16x16x32_bf16(E.v, ONES, vzero, 0, 0, 0);
            f32x4 D0 = __builtin_amdgcn_mfma_f32_16x16x32_bf16(E.v, W[0], vzero, 0, 0, 0);
            f32x4 D1 = __builtin_amdgcn_mfma_f32_16x16x32_bf16(E.v, W[1], vzero, 0, 0, 0);
            f32x4 D2 = __builtin_amdgcn_mfma_f32_16x16x32_bf16(E.v, W[2], vzero, 0, 0, 0);
            f32x4 D3 = __builtin_amdgcn_mfma_f32_16x16x32_bf16(E.v, W[3], vzero, 0, 0, 0);
            #pragma unroll
            for (int r = 0; r < 4; ++r) {
                const float inv = __builtin_amdgcn_rcpf(sv[r]);
                S[rbk][0][r] += D0[r] * inv;
                S[rbk][1][r] += D1[r] * inv;
                S[rbk][2][r] += D2[r] * inv;
                S[rbk][3][r] += D3[r] * inv;
            }
        }
    }

    // ---- reduce partial S across the 8 waves through LDS (Pbuf overlay, pitch 20) ----
    __syncthreads();                            // all Pbuf/Xf/Kd reads done
    float* Sred = (float*)Pbuf;                 // [8 waves][64 lanes][20 floats] = 40 KB
    const int si = (wv * 64 + lane) * 20;
    f32x4 F0 = vzero, F1 = vzero, F2 = vzero, F3 = vzero;  // meaningful for wv<4

    #pragma unroll
    for (int ph = 0; ph < 4; ++ph) {
        *(f32x4*)&Sred[si + 0]  = S[ph][0];
        *(f32x4*)&Sred[si + 4]  = S[ph][1];
        *(f32x4*)&Sred[si + 8]  = S[ph][2];
        *(f32x4*)&Sred[si + 12] = S[ph][3];
        __syncthreads();
        if (wv == ph) {
            #pragma unroll
            for (int s = 0; s < 8; ++s) {
                const int b0 = (s * 64 + lane) * 20;
                F0 += *(const f32x4*)&Sred[b0 + 0];
                F1 += *(const f32x4*)&Sred[b0 + 4];
                F2 += *(const f32x4*)&Sred[b0 + 8];
                F3 += *(const f32x4*)&Sred[b0 + 12];
            }
        }
        __syncthreads();
    }

    // ---- epilogue (waves 0..3; wave wv owns rows wv*16 + q*4 + r) ----
    if (wv < 4) {
        const float sc = 1.f / 64.f;
        #pragma unroll
        for (int r = 0; r < 4; ++r) {
            const float e0 = __expf(F0[r] * sc);
            const float e1 = __expf(F1[r] * sc);
            const float e2 = __expf(F2[r] * sc);
            const float e3 = __expf(F3[r] * sc);
            float s = e0 + e1 + e2 + e3;
            s += __shfl_xor(s, 1);
            s += __shfl_xor(s, 2);
            s += __shfl_xor(s, 4);
            s += __shfl_xor(s, 8);
            const float inv = 1.f / s;
            const int b = bt * 64 + wv * 16 + q * 4 + r;
            float* o = out + ((size_t)a * B_ + b) * F_ + c;
            o[0]  = e0 * inv;
            o[16] = e1 * inv;
            o[32] = e2 * inv;
            o[48] = e3 * inv;
        }
    }
}

extern "C" void kernel_launch(void* const* d_in, const int* in_sizes, int n_in,
                              void* d_out, int out_size, void* d_ws, size_t ws_size,
                              hipStream_t stream) {
    (void)in_sizes; (void)n_in; (void)out_size; (void)ws_size;
    const float* x    = (const float*)d_in[0];   // [B, F]
    const float* kern = (const float*)d_in[1];   // [F, A, F, U]
    float* out        = (float*)d_out;           // [A, B, F]
    unsigned char* ws = (unsigned char*)d_ws;    // ~4.1 MB used

    hipLaunchKernelGGL(ife_prep, dim3(F_ * A_), dim3(256), 0, stream, kern, ws);
    hipLaunchKernelGGL(ife_main, dim3(B_ / 64, A_), dim3(512), 0, stream, x, ws, out);
}

// Round 7
// 99.971 us; speedup vs baseline: 1.0915x; 1.0915x over previous
//
#include <hip/hip_runtime.h>
#include <hip/hip_bf16.h>
#include <math.h>

#define B_ 4096
#define F_ 64
#define A_ 8
#define U_ 32

typedef float f32x4 __attribute__((ext_vector_type(4)));
typedef short bf16x8 __attribute__((ext_vector_type(8)));

// ws layout:
//   [0, 4 MB): frag blob, per (a,j) 8192 B, index (a*64+j):
//     [0,4096):  K frags, fragid = kc*2+ut, 64 lanes x 16 B:
//                bf16 K[f = kc*32 + q*8 + i][u = ut*16 + c]
//                (used as the A operand of Z^T = K^T-slice · X^T)
//     [4096,8192): W frags, fragid = ft, 64 lanes x 16 B, u-PERMUTED to match
//                the Z^T output slot order: slot i of lane (q,c) holds
//                bf16 exp(2*K[f = ft*16 + c][u = pi(q,i)]),
//                pi(q,i) = (i<4) ? 4q+i : 16 + 4q + (i-4)
//   [4 MB, 4 MB + 64 KB): Kd fp32 (bf16-rounded): [a*64+j][32] = K[j,a][j][u]
#define KD_OFF (4ull << 20)

static __device__ __forceinline__ unsigned int pk_bf16(float lo, float hi) {
    union { __hip_bfloat162 h2; unsigned int u; } cv;
    cv.h2 = __float22bfloat162_rn(make_float2(lo, hi));
    return cv.u;
}
// round fp32 -> bf16 -> fp32 (match what the MFMA actually sees)
static __device__ __forceinline__ float rb(float f) {
    unsigned int u = __float_as_uint(f);
    u += 0x7FFFu + ((u >> 16) & 1u);
    return __uint_as_float(u & 0xFFFF0000u);
}

// ---------------- prep: one block per (a,j); stage 8 KB, emit frags + Kd ----------------
__global__ __launch_bounds__(256) void ife_prep(const float* __restrict__ kern,
                                                unsigned char* __restrict__ ws)
{
    const int bid = blockIdx.x;           // a*64 + j
    const int a = bid >> 6, j = bid & 63;
    const int t = threadIdx.x;
    __shared__ float st[64][36];          // [f][u], pitch 36 (16B-aligned float4 slots)

    const float* src = kern + ((size_t)j * A_ + a) * (F_ * U_);
    {
        const int f = t >> 2, u0 = (t & 3) * 8;
        *(float4*)&st[f][u0]     = *(const float4*)&src[f * U_ + u0];
        *(float4*)&st[f][u0 + 4] = *(const float4*)&src[f * U_ + u0 + 4];
    }
    __syncthreads();

    unsigned char* dst = ws + (size_t)bid * 8192;
    const int fragid = t >> 6, lane = t & 63, q = lane >> 4, c = lane & 15;

    // K frag (fragid = kc*2 + ut) — unchanged layout
    {
        const int kc = fragid >> 1, ut = fragid & 1;
        const int f0 = kc * 32 + q * 8, u = ut * 16 + c;
        unsigned int w[4];
        #pragma unroll
        for (int i = 0; i < 4; ++i)
            w[i] = pk_bf16(st[f0 + 2 * i][u], st[f0 + 2 * i + 1][u]);
        *(uint4*)(dst + fragid * 1024 + lane * 16) = make_uint4(w[0], w[1], w[2], w[3]);
    }
    // W frag (fragid = ft), u-permuted: slots = {4q..4q+3, 16+4q..16+4q+3}
    {
        const int f = fragid * 16 + c;
        const float4 wa = *(const float4*)&st[f][q * 4];        // u = 4q .. 4q+3
        const float4 wb = *(const float4*)&st[f][16 + q * 4];   // u = 16+4q .. 16+4q+3
        unsigned int w[4];
        w[0] = pk_bf16(__expf(2.f * wa.x), __expf(2.f * wa.y));
        w[1] = pk_bf16(__expf(2.f * wa.z), __expf(2.f * wa.w));
        w[2] = pk_bf16(__expf(2.f * wb.x), __expf(2.f * wb.y));
        w[3] = pk_bf16(__expf(2.f * wb.z), __expf(2.f * wb.w));
        *(uint4*)(dst + 4096 + fragid * 1024 + lane * 16) = make_uint4(w[0], w[1], w[2], w[3]);
    }
    // Kd (bf16-rounded so the rank-1 correction exactly cancels the MFMA j-term)
    if (t < U_)
        ((float*)(ws + KD_OFF))[(size_t)bid * U_ + t] = rb(st[j][t]);
}

// ---------------- main: (a, 64-row tile); 8 waves = 2 j-groups x 4 row-waves --------------
// The per-j LDS write->drain->read transpose of E (the R0-R4 structural floor) is gone:
// Z is computed TRANSPOSED via operand swap mfma(K_frag, X_frag) — A and B fragments share
// the same per-lane register layout, so the same ws blob serves. Each lane then holds 8
// u-values of ONE b-row; softmax denom = in-lane adds + 2 shfl_xor. W frags are stored
// u-permuted so the packed e registers feed mfma(W, E, C) directly. No Pbuf, no drain.
__global__ __launch_bounds__(512, 4) void ife_main(const float* __restrict__ x,
                                                   const unsigned char* __restrict__ ws,
                                                   float* __restrict__ out)
{
    const int a = blockIdx.y, bt = blockIdx.x, t = threadIdx.x;
    const int wv = t >> 6, lane = t & 63, q = lane >> 4, c = lane & 15;
    const int grp = wv >> 2, w4 = wv & 3;

    // One shared pool: Xf [64][66] (4224 f) + Kd [64][32] (2048 f) = 25.1 KB.
    // After the j-loop it is reused (post-barrier) as the S-reduction buffer (pitch 20).
    __shared__ __align__(16) float SH[6272];
    float* Xf = SH;                  // Xf[row][cc] = SH[row*66 + cc]
    float* Kd = SH + 4224;           // Kd[j][u]    = SH[4224 + j*32 + u]

    // X frags (lane holds X[b-row = c][f = kc*32 + q*8 + i]) — B operand of Z^T
    bf16x8 Xh[2];
    {
        const float* xr = x + (size_t)(bt * 64 + w4 * 16 + c) * F_;
        #pragma unroll
        for (int kc = 0; kc < 2; ++kc) {
            const float4 va = *(const float4*)&xr[kc * 32 + q * 8];
            const float4 vb = *(const float4*)&xr[kc * 32 + q * 8 + 4];
            union { unsigned int u[4]; bf16x8 v; } H;
            H.u[0] = pk_bf16(va.x, va.y);
            H.u[1] = pk_bf16(va.z, va.w);
            H.u[2] = pk_bf16(vb.x, vb.y);
            H.u[3] = pk_bf16(vb.z, vb.w);
            Xh[kc] = H.v;
        }
    }
    // Xf (bf16-rounded values, fp32 storage); 512 threads, scalar stores (pitch 66)
    {
        const int row = t >> 3, cb = (t & 7) * 8;
        const float* xsrc = x + (size_t)(bt * 64 + row) * F_ + cb;
        const float4 v0 = *(const float4*)&xsrc[0];
        const float4 v1 = *(const float4*)&xsrc[4];
        float* xd = Xf + row * 66 + cb;
        xd[0] = rb(v0.x); xd[1] = rb(v0.y); xd[2] = rb(v0.z); xd[3] = rb(v0.w);
        xd[4] = rb(v1.x); xd[5] = rb(v1.y); xd[6] = rb(v1.z); xd[7] = rb(v1.w);
    }
    // Kd stage (contiguous 8 KB); 512 threads x 1 float4
    {
        const float* kd = (const float*)(ws + KD_OFF) + (size_t)a * 64 * U_;
        const int jj = t >> 3, u0 = (t & 7) * 4;
        *(float4*)&Kd[jj * 32 + u0] = *(const float4*)&kd[jj * U_ + u0];
    }
    __syncthreads();   // staging barrier

    const unsigned char* fbase = ws + (size_t)a * 64 * 8192 + (size_t)lane * 16;
    const f32x4 vzero = (f32x4){0.f, 0.f, 0.f, 0.f};

    f32x4 S0 = vzero, S1 = vzero, S2 = vzero, S3 = vzero;   // S[ft]: score[row=c][f=ft*16+4q+r]

    const int jb = grp * 32;
    #pragma unroll 1
    for (int jj = 0; jj < 32; ++jj) {
        const int j = jb + jj;
        const unsigned char* p = fbase + (size_t)j * 8192;

        const bf16x8 K0 = *(const bf16x8*)(p + 0);
        const bf16x8 K1 = *(const bf16x8*)(p + 1024);
        const bf16x8 K2 = *(const bf16x8*)(p + 2048);
        const bf16x8 K3 = *(const bf16x8*)(p + 3072);
        const bf16x8 W0 = *(const bf16x8*)(p + 4096);
        const bf16x8 W1 = *(const bf16x8*)(p + 5120);
        const bf16x8 W2 = *(const bf16x8*)(p + 6144);
        const bf16x8 W3 = *(const bf16x8*)(p + 7168);

        // per-j scalars: xj for this lane's row; kd for this lane's 8 u-slots
        const float xj = Xf[(w4 * 16 + c) * 66 + j];
        const f32x4 kda = *(const f32x4*)&Kd[j * 32 + q * 4];        // u = 4q+r
        const f32x4 kdb = *(const f32x4*)&Kd[j * 32 + 16 + q * 4];   // u = 16+4q+r

        // Z^T: lane (q,c) gets Z[u][row=c]: ZA -> u = 4q+r, ZB -> u = 16+4q+r
        f32x4 ZA = vzero, ZB = vzero;
        ZA = __builtin_amdgcn_mfma_f32_16x16x32_bf16(K0, Xh[0], ZA, 0, 0, 0);
        ZA = __builtin_amdgcn_mfma_f32_16x16x32_bf16(K2, Xh[1], ZA, 0, 0, 0);
        ZB = __builtin_amdgcn_mfma_f32_16x16x32_bf16(K1, Xh[0], ZB, 0, 0, 0);
        ZB = __builtin_amdgcn_mfma_f32_16x16x32_bf16(K3, Xh[1], ZB, 0, 0, 0);

        // rank-1 mask correction + exp; pack to bf16 (E frag, u-permuted slot order)
        float eA[4], eB[4];
        #pragma unroll
        for (int r = 0; r < 4; ++r) {
            eA[r] = __expf(ZA[r] - xj * kda[r]);
            eB[r] = __expf(ZB[r] - xj * kdb[r]);
        }
        union { unsigned int u[4]; bf16x8 v; } E;
        E.u[0] = pk_bf16(eA[0], eA[1]);
        E.u[1] = pk_bf16(eA[2], eA[3]);
        E.u[2] = pk_bf16(eB[0], eB[1]);
        E.u[3] = pk_bf16(eB[2], eB[3]);

        // denominator from the bf16-ROUNDED values (matches what PV sums), then
        // cross-q reduce: each lane owns 8 of the row's 32 u's.
        float s = 0.f;
        #pragma unroll
        for (int i = 0; i < 4; ++i) {
            const float lo = __uint_as_float(E.u[i] << 16);
            const float hi = __uint_as_float(E.u[i] & 0xFFFF0000u);
            s += lo + hi;
        }
        s += __shfl_xor(s, 16, 64);
        s += __shfl_xor(s, 32, 64);
        const float inv = __builtin_amdgcn_rcpf(s);

        // PV: D[ft] = W[ft] · E  (u contraction; both sides share the same u-permutation)
        const f32x4 D0 = __builtin_amdgcn_mfma_f32_16x16x32_bf16(W0, E.v, vzero, 0, 0, 0);
        const f32x4 D1 = __builtin_amdgcn_mfma_f32_16x16x32_bf16(W1, E.v, vzero, 0, 0, 0);
        const f32x4 D2 = __builtin_amdgcn_mfma_f32_16x16x32_bf16(W2, E.v, vzero, 0, 0, 0);
        const f32x4 D3 = __builtin_amdgcn_mfma_f32_16x16x32_bf16(W3, E.v, vzero, 0, 0, 0);
        #pragma unroll
        for (int r = 0; r < 4; ++r) {
            S0[r] += D0[r] * inv;
            S1[r] += D1[r] * inv;
            S2[r] += D2[r] * inv;
            S3[r] += D3[r] * inv;
        }
    }

    // ---- combine the two j-groups' partial S through LDS (overlay on SH, pitch 20) ----
    __syncthreads();                            // all Xf/Kd reads done
    float* Sred = SH;                           // [w4*64+lane][20] — 5120 floats used
    if (grp == 1) {
        float* pp = Sred + (size_t)(w4 * 64 + lane) * 20;
        *(f32x4*)(pp + 0)  = S0;
        *(f32x4*)(pp + 4)  = S1;
        *(f32x4*)(pp + 8)  = S2;
        *(f32x4*)(pp + 12) = S3;
    }
    __syncthreads();
    if (grp == 0) {
        const float* pp = Sred + (size_t)(w4 * 64 + lane) * 20;
        S0 += *(const f32x4*)(pp + 0);
        S1 += *(const f32x4*)(pp + 4);
        S2 += *(const f32x4*)(pp + 8);
        S3 += *(const f32x4*)(pp + 12);

        // epilogue: mean over j, softmax over f. Lane (q,c) holds row c's f = ft*16+4q+r.
        const float sc = 1.f / 64.f;
        float ex[4][4];
        float part = 0.f;
        #pragma unroll
        for (int r = 0; r < 4; ++r) {
            ex[0][r] = __expf(S0[r] * sc);
            ex[1][r] = __expf(S1[r] * sc);
            ex[2][r] = __expf(S2[r] * sc);
            ex[3][r] = __expf(S3[r] * sc);
            part += ex[0][r] + ex[1][r] + ex[2][r] + ex[3][r];
        }
        part += __shfl_xor(part, 16, 64);
        part += __shfl_xor(part, 32, 64);
        const float inv = 1.f / part;

        const int b = bt * 64 + w4 * 16 + c;
        float* o = out + ((size_t)a * B_ + b) * F_;
        #pragma unroll
        for (int ft = 0; ft < 4; ++ft) {
            float4 v;
            v.x = ex[ft][0] * inv;
            v.y = ex[ft][1] * inv;
            v.z = ex[ft][2] * inv;
            v.w = ex[ft][3] * inv;
            *(float4*)&o[ft * 16 + q * 4] = v;
        }
    }
}

extern "C" void kernel_launch(void* const* d_in, const int* in_sizes, int n_in,
                              void* d_out, int out_size, void* d_ws, size_t ws_size,
                              hipStream_t stream) {
    (void)in_sizes; (void)n_in; (void)out_size; (void)ws_size;
    const float* x    = (const float*)d_in[0];   // [B, F]
    const float* kern = (const float*)d_in[1];   // [F, A, F, U]
    float* out        = (float*)d_out;           // [A, B, F]
    unsigned char* ws = (unsigned char*)d_ws;    // ~4.1 MB used

    hipLaunchKernelGGL(ife_prep, dim3(F_ * A_), dim3(256), 0, stream, kern, ws);
    hipLaunchKernelGGL(ife_main, dim3(B_ / 64, A_), dim3(512), 0, stream, x, ws, out);
}

// Round 9
// 99.346 us; speedup vs baseline: 1.0984x; 1.0063x over previous
//
#include <hip/hip_runtime.h>
#include <hip/hip_bf16.h>
#include <math.h>

#define B_ 4096
#define F_ 64
#define A_ 8
#define U_ 32

typedef float f32x4 __attribute__((ext_vector_type(4)));
typedef short bf16x8 __attribute__((ext_vector_type(8)));

// ws layout:
//   [0, 4 MB): frag blob, per (a,j) 8192 B, index (a*64+j):
//     [0,4096):  K frags, fragid = kc*2+ut, 64 lanes x 16 B:
//                bf16 K[f = kc*32 + q*8 + i][u = ut*16 + c]
//                (used as the A operand of Z^T = K^T-slice · X^T)
//     [4096,8192): W frags, fragid = ft, 64 lanes x 16 B, u-PERMUTED to match
//                the Z^T output slot order: slot i of lane (q,c) holds
//                bf16 exp(2*K[f = ft*16 + c][u = pi(q,i)]),
//                pi(q,i) = (i<4) ? 4q+i : 16 + 4q + (i-4)
//   [4 MB, 4 MB + 64 KB): Kd fp32 (bf16-rounded): [a*64+j][32] = K[j,a][j][u]
#define KD_OFF (4ull << 20)

static __device__ __forceinline__ unsigned int pk_bf16(float lo, float hi) {
    union { __hip_bfloat162 h2; unsigned int u; } cv;
    cv.h2 = __float22bfloat162_rn(make_float2(lo, hi));
    return cv.u;
}
// round fp32 -> bf16 -> fp32 (match what the MFMA actually sees)
static __device__ __forceinline__ float rb(float f) {
    unsigned int u = __float_as_uint(f);
    u += 0x7FFFu + ((u >> 16) & 1u);
    return __uint_as_float(u & 0xFFFF0000u);
}

// ---------------- prep: one block per (a,j); stage 8 KB, emit frags + Kd ----------------
__global__ __launch_bounds__(256) void ife_prep(const float* __restrict__ kern,
                                                unsigned char* __restrict__ ws)
{
    const int bid = blockIdx.x;           // a*64 + j
    const int a = bid >> 6, j = bid & 63;
    const int t = threadIdx.x;
    __shared__ float st[64][36];          // [f][u], pitch 36 (16B-aligned float4 slots)

    const float* src = kern + ((size_t)j * A_ + a) * (F_ * U_);
    {
        const int f = t >> 2, u0 = (t & 3) * 8;
        *(float4*)&st[f][u0]     = *(const float4*)&src[f * U_ + u0];
        *(float4*)&st[f][u0 + 4] = *(const float4*)&src[f * U_ + u0 + 4];
    }
    __syncthreads();

    unsigned char* dst = ws + (size_t)bid * 8192;
    const int fragid = t >> 6, lane = t & 63, q = lane >> 4, c = lane & 15;

    // K frag (fragid = kc*2 + ut)
    {
        const int kc = fragid >> 1, ut = fragid & 1;
        const int f0 = kc * 32 + q * 8, u = ut * 16 + c;
        unsigned int w[4];
        #pragma unroll
        for (int i = 0; i < 4; ++i)
            w[i] = pk_bf16(st[f0 + 2 * i][u], st[f0 + 2 * i + 1][u]);
        *(uint4*)(dst + fragid * 1024 + lane * 16) = make_uint4(w[0], w[1], w[2], w[3]);
    }
    // W frag (fragid = ft), u-permuted: slots = {4q..4q+3, 16+4q..16+4q+3}
    {
        const int f = fragid * 16 + c;
        const float4 wa = *(const float4*)&st[f][q * 4];        // u = 4q .. 4q+3
        const float4 wb = *(const float4*)&st[f][16 + q * 4];   // u = 16+4q .. 16+4q+3
        unsigned int w[4];
        w[0] = pk_bf16(__expf(2.f * wa.x), __expf(2.f * wa.y));
        w[1] = pk_bf16(__expf(2.f * wa.z), __expf(2.f * wa.w));
        w[2] = pk_bf16(__expf(2.f * wb.x), __expf(2.f * wb.y));
        w[3] = pk_bf16(__expf(2.f * wb.z), __expf(2.f * wb.w));
        *(uint4*)(dst + 4096 + fragid * 1024 + lane * 16) = make_uint4(w[0], w[1], w[2], w[3]);
    }
    // Kd (bf16-rounded so the rank-1 correction exactly cancels the MFMA j-term)
    if (t < U_)
        ((float*)(ws + KD_OFF))[(size_t)bid * U_ + t] = rb(st[j][t]);
}

// ---------------- main: (a, 64-row tile); 8 waves = 2 j-groups x 4 row-waves --------------
// R8's asm prefetch faulted (async loads into compiler-managed registers are unsafe).
// This version gets the same latency overlap with compiler-safe ILP: each wave processes
// TWO independent j-streams per loop body (j and j+16 of its 32-j range). Both streams'
// K-loads issue together; the compiler's counted vmcnt waits let stream B's loads ride
// under stream A's compute. Denominator via MFMA against a ONES A-frag (no shfl chain).
// K and W frags are not co-resident (W loaded after Z) to stay under the 128-VGPR cap.
__global__ __launch_bounds__(512, 4) void ife_main(const float* __restrict__ x,
                                                   const unsigned char* __restrict__ ws,
                                                   float* __restrict__ out)
{
    const int a = blockIdx.y, bt = blockIdx.x, t = threadIdx.x;
    const int wv = t >> 6, lane = t & 63, q = lane >> 4, c = lane & 15;
    const int grp = wv >> 2, w4 = wv & 3;

    // One shared pool: Xf [64][66] (4224 f) + Kd [64][32] (2048 f) = 25.1 KB.
    // After the j-loop it is reused (post-barrier) as the S-reduction buffer (pitch 20).
    __shared__ __align__(16) float SH[6272];
    float* Xf = SH;                  // Xf[row][cc] = SH[row*66 + cc]
    float* Kd = SH + 4224;           // Kd[j][u]    = SH[4224 + j*32 + u]

    // X frags (lane holds X[b-row = c][f = kc*32 + q*8 + i]) — B operand of Z^T
    bf16x8 Xh[2];
    {
        const float* xr = x + (size_t)(bt * 64 + w4 * 16 + c) * F_;
        #pragma unroll
        for (int kc = 0; kc < 2; ++kc) {
            const float4 va = *(const float4*)&xr[kc * 32 + q * 8];
            const float4 vb = *(const float4*)&xr[kc * 32 + q * 8 + 4];
            union { unsigned int u[4]; bf16x8 v; } H;
            H.u[0] = pk_bf16(va.x, va.y);
            H.u[1] = pk_bf16(va.z, va.w);
            H.u[2] = pk_bf16(vb.x, vb.y);
            H.u[3] = pk_bf16(vb.z, vb.w);
            Xh[kc] = H.v;
        }
    }
    // Xf (bf16-rounded values, fp32 storage); 512 threads, scalar stores (pitch 66)
    {
        const int row = t >> 3, cb = (t & 7) * 8;
        const float* xsrc = x + (size_t)(bt * 64 + row) * F_ + cb;
        const float4 v0 = *(const float4*)&xsrc[0];
        const float4 v1 = *(const float4*)&xsrc[4];
        float* xd = Xf + row * 66 + cb;
        xd[0] = rb(v0.x); xd[1] = rb(v0.y); xd[2] = rb(v0.z); xd[3] = rb(v0.w);
        xd[4] = rb(v1.x); xd[5] = rb(v1.y); xd[6] = rb(v1.z); xd[7] = rb(v1.w);
    }
    // Kd stage (contiguous 8 KB); 512 threads x 1 float4
    {
        const float* kd = (const float*)(ws + KD_OFF) + (size_t)a * 64 * U_;
        const int jj = t >> 3, u0 = (t & 7) * 4;
        *(float4*)&Kd[jj * 32 + u0] = *(const float4*)&kd[jj * U_ + u0];
    }
    __syncthreads();   // staging barrier

    const unsigned char* fbase = ws + (size_t)a * 64 * 8192 + (size_t)lane * 16;
    const f32x4 vzero = (f32x4){0.f, 0.f, 0.f, 0.f};

    union { unsigned int u[4]; bf16x8 v; } oc;
    oc.u[0] = 0x3F803F80u; oc.u[1] = 0x3F803F80u; oc.u[2] = 0x3F803F80u; oc.u[3] = 0x3F803F80u;
    const bf16x8 ONES = oc.v;

    f32x4 S0 = vzero, S1 = vzero, S2 = vzero, S3 = vzero;   // S[ft]: score[row=c][f=ft*16+4q+r]

    const int jb = grp * 32;
    const int xfrow = (w4 * 16 + c) * 66;

    #pragma unroll 1
    for (int jj = 0; jj < 16; ++jj) {
        const int ja = jb + jj;            // stream A
        const int jc = jb + 16 + jj;       // stream B (independent)
        const unsigned char* pa = fbase + (size_t)ja * 8192;
        const unsigned char* pc = fbase + (size_t)jc * 8192;

        // K frags, both streams (8 x 16B loads in flight together)
        const bf16x8 KA0 = *(const bf16x8*)(pa);
        const bf16x8 KA1 = *(const bf16x8*)(pa + 1024);
        const bf16x8 KA2 = *(const bf16x8*)(pa + 2048);
        const bf16x8 KA3 = *(const bf16x8*)(pa + 3072);
        const bf16x8 KC0 = *(const bf16x8*)(pc);
        const bf16x8 KC1 = *(const bf16x8*)(pc + 1024);
        const bf16x8 KC2 = *(const bf16x8*)(pc + 2048);
        const bf16x8 KC3 = *(const bf16x8*)(pc + 3072);

        // per-j scalars (LDS broadcast reads), both streams
        const float xjA = Xf[xfrow + ja];
        const float xjC = Xf[xfrow + jc];
        const f32x4 kdaA = *(const f32x4*)&Kd[ja * 32 + q * 4];
        const f32x4 kdbA = *(const f32x4*)&Kd[ja * 32 + 16 + q * 4];
        const f32x4 kdaC = *(const f32x4*)&Kd[jc * 32 + q * 4];
        const f32x4 kdbC = *(const f32x4*)&Kd[jc * 32 + 16 + q * 4];

        // Z^T, both streams: lane (q,c) gets Z[u][row=c]; Z0 -> u=4q+r, Z1 -> u=16+4q+r
        f32x4 Z0A = vzero, Z1A = vzero, Z0C = vzero, Z1C = vzero;
        Z0A = __builtin_amdgcn_mfma_f32_16x16x32_bf16(KA0, Xh[0], Z0A, 0, 0, 0);
        Z0A = __builtin_amdgcn_mfma_f32_16x16x32_bf16(KA2, Xh[1], Z0A, 0, 0, 0);
        Z1A = __builtin_amdgcn_mfma_f32_16x16x32_bf16(KA1, Xh[0], Z1A, 0, 0, 0);
        Z1A = __builtin_amdgcn_mfma_f32_16x16x32_bf16(KA3, Xh[1], Z1A, 0, 0, 0);
        Z0C = __builtin_amdgcn_mfma_f32_16x16x32_bf16(KC0, Xh[0], Z0C, 0, 0, 0);
        Z0C = __builtin_amdgcn_mfma_f32_16x16x32_bf16(KC2, Xh[1], Z0C, 0, 0, 0);
        Z1C = __builtin_amdgcn_mfma_f32_16x16x32_bf16(KC1, Xh[0], Z1C, 0, 0, 0);
        Z1C = __builtin_amdgcn_mfma_f32_16x16x32_bf16(KC3, Xh[1], Z1C, 0, 0, 0);

        // W frags, both streams (issued before exp; exp covers their latency)
        const bf16x8 WA0 = *(const bf16x8*)(pa + 4096);
        const bf16x8 WA1 = *(const bf16x8*)(pa + 5120);
        const bf16x8 WA2 = *(const bf16x8*)(pa + 6144);
        const bf16x8 WA3 = *(const bf16x8*)(pa + 7168);
        const bf16x8 WC0 = *(const bf16x8*)(pc + 4096);
        const bf16x8 WC1 = *(const bf16x8*)(pc + 5120);
        const bf16x8 WC2 = *(const bf16x8*)(pc + 6144);
        const bf16x8 WC3 = *(const bf16x8*)(pc + 7168);

        // rank-1 mask correction + exp; pack to bf16 (E frag, u-permuted slot order)
        union { unsigned int u[4]; bf16x8 v; } EA, EC;
        EA.u[0] = pk_bf16(__expf(Z0A[0] - xjA * kdaA[0]), __expf(Z0A[1] - xjA * kdaA[1]));
        EA.u[1] = pk_bf16(__expf(Z0A[2] - xjA * kdaA[2]), __expf(Z0A[3] - xjA * kdaA[3]));
        EA.u[2] = pk_bf16(__expf(Z1A[0] - xjA * kdbA[0]), __expf(Z1A[1] - xjA * kdbA[1]));
        EA.u[3] = pk_bf16(__expf(Z1A[2] - xjA * kdbA[2]), __expf(Z1A[3] - xjA * kdbA[3]));
        EC.u[0] = pk_bf16(__expf(Z0C[0] - xjC * kdaC[0]), __expf(Z0C[1] - xjC * kdaC[1]));
        EC.u[1] = pk_bf16(__expf(Z0C[2] - xjC * kdaC[2]), __expf(Z0C[3] - xjC * kdaC[3]));
        EC.u[2] = pk_bf16(__expf(Z1C[0] - xjC * kdbC[0]), __expf(Z1C[1] - xjC * kdbC[1]));
        EC.u[3] = pk_bf16(__expf(Z1C[2] - xjC * kdbC[2]), __expf(Z1C[3] - xjC * kdbC[3]));

        // denominator via MFMA vs ONES A-frag: sv[r] = sum_u E[u][c] (same in all r);
        // sums the bf16-ROUNDED values — matches what PV sums.
        const f32x4 svA = __builtin_amdgcn_mfma_f32_16x16x32_bf16(ONES, EA.v, vzero, 0, 0, 0);
        const f32x4 svC = __builtin_amdgcn_mfma_f32_16x16x32_bf16(ONES, EC.v, vzero, 0, 0, 0);

        // PV, both streams: D[ft] = W[ft] · E (u contraction; shared u-permutation)
        const f32x4 D0A = __builtin_amdgcn_mfma_f32_16x16x32_bf16(WA0, EA.v, vzero, 0, 0, 0);
        const f32x4 D1A = __builtin_amdgcn_mfma_f32_16x16x32_bf16(WA1, EA.v, vzero, 0, 0, 0);
        const f32x4 D2A = __builtin_amdgcn_mfma_f32_16x16x32_bf16(WA2, EA.v, vzero, 0, 0, 0);
        const f32x4 D3A = __builtin_amdgcn_mfma_f32_16x16x32_bf16(WA3, EA.v, vzero, 0, 0, 0);
        const f32x4 D0C = __builtin_amdgcn_mfma_f32_16x16x32_bf16(WC0, EC.v, vzero, 0, 0, 0);
        const f32x4 D1C = __builtin_amdgcn_mfma_f32_16x16x32_bf16(WC1, EC.v, vzero, 0, 0, 0);
        const f32x4 D2C = __builtin_amdgcn_mfma_f32_16x16x32_bf16(WC2, EC.v, vzero, 0, 0, 0);
        const f32x4 D3C = __builtin_amdgcn_mfma_f32_16x16x32_bf16(WC3, EC.v, vzero, 0, 0, 0);

        const float invA = __builtin_amdgcn_rcpf(svA[0]);
        const float invC = __builtin_amdgcn_rcpf(svC[0]);
        #pragma unroll
        for (int r = 0; r < 4; ++r) {
            S0[r] += D0A[r] * invA; S0[r] += D0C[r] * invC;
            S1[r] += D1A[r] * invA; S1[r] += D1C[r] * invC;
            S2[r] += D2A[r] * invA; S2[r] += D2C[r] * invC;
            S3[r] += D3A[r] * invA; S3[r] += D3C[r] * invC;
        }
    }

    // ---- combine the two j-groups' partial S through LDS (overlay on SH, pitch 20) ----
    __syncthreads();                            // all Xf/Kd reads done
    float* Sred = SH;                           // [w4*64+lane][20] — 5120 floats used
    if (grp == 1) {
        float* pp = Sred + (size_t)(w4 * 64 + lane) * 20;
        *(f32x4*)(pp + 0)  = S0;
        *(f32x4*)(pp + 4)  = S1;
        *(f32x4*)(pp + 8)  = S2;
        *(f32x4*)(pp + 12) = S3;
    }
    __syncthreads();
    if (grp == 0) {
        const float* pp = Sred + (size_t)(w4 * 64 + lane) * 20;
        S0 += *(const f32x4*)(pp + 0);
        S1 += *(const f32x4*)(pp + 4);
        S2 += *(const f32x4*)(pp + 8);
        S3 += *(const f32x4*)(pp + 12);

        // epilogue: mean over j, softmax over f. Lane (q,c) holds row c's f = ft*16+4q+r.
        const float sc = 1.f / 64.f;
        float ex[4][4];
        float part = 0.f;
        #pragma unroll
        for (int r = 0; r < 4; ++r) {
            ex[0][r] = __expf(S0[r] * sc);
            ex[1][r] = __expf(S1[r] * sc);
            ex[2][r] = __expf(S2[r] * sc);
            ex[3][r] = __expf(S3[r] * sc);
            part += ex[0][r] + ex[1][r] + ex[2][r] + ex[3][r];
        }
        part += __shfl_xor(part, 16, 64);
        part += __shfl_xor(part, 32, 64);
        const float inv = 1.f / part;

        const int b = bt * 64 + w4 * 16 + c;
        float* o = out + ((size_t)a * B_ + b) * F_;
        #pragma unroll
        for (int ft = 0; ft < 4; ++ft) {
            float4 v;
            v.x = ex[ft][0] * inv;
            v.y = ex[ft][1] * inv;
            v.z = ex[ft][2] * inv;
            v.w = ex[ft][3] * inv;
            *(float4*)&o[ft * 16 + q * 4] = v;
        }
    }
}

extern "C" void kernel_launch(void* const* d_in, const int* in_sizes, int n_in,
                              void* d_out, int out_size, void* d_ws, size_t ws_size,
                              hipStream_t stream) {
    (void)in_sizes; (void)n_in; (void)out_size; (void)ws_size;
    const float* x    = (const float*)d_in[0];   // [B, F]
    const float* kern = (const float*)d_in[1];   // [F, A, F, U]
    float* out        = (float*)d_out;           // [A, B, F]
    unsigned char* ws = (unsigned char*)d_ws;    // ~4.1 MB used

    hipLaunchKernelGGL(ife_prep, dim3(F_ * A_), dim3(256), 0, stream, kern, ws);
    hipLaunchKernelGGL(ife_main, dim3(B_ / 64, A_), dim3(512), 0, stream, x, ws, out);
}

// Round 10
// 96.162 us; speedup vs baseline: 1.1347x; 1.0331x over previous
//
#include <hip/hip_runtime.h>
#include <hip/hip_bf16.h>
#include <math.h>

#define B_ 4096
#define F_ 64
#define A_ 8
#define U_ 32

typedef float f32x4 __attribute__((ext_vector_type(4)));
typedef short bf16x8 __attribute__((ext_vector_type(8)));

// ws layout:
//   [0, 4 MB): frag blob, per (a,j) 8192 B, index (a*64+j):
//     [0,4096):  K frags, fragid = kc*2+ut, 64 lanes x 16 B:
//                bf16 K[f = kc*32 + q*8 + i][u = ut*16 + c]
//                (used as the A operand of Z^T = K^T-slice · X^T)
//     [4096,8192): W frags, fragid = ft, 64 lanes x 16 B, u-PERMUTED to match
//                the Z^T output slot order: slot i of lane (q,c) holds
//                bf16 exp(2*K[f = ft*16 + c][u = pi(q,i)]),
//                pi(q,i) = (i<4) ? 4q+i : 16 + 4q + (i-4)
//   [4 MB, 4 MB + 64 KB): Kd fp32 (bf16-rounded): [a*64+j][32] = K[j,a][j][u]
#define KD_OFF (4ull << 20)

static __device__ __forceinline__ unsigned int pk_bf16(float lo, float hi) {
    union { __hip_bfloat162 h2; unsigned int u; } cv;
    cv.h2 = __float22bfloat162_rn(make_float2(lo, hi));
    return cv.u;
}
// round fp32 -> bf16 -> fp32 (match what the MFMA actually sees)
static __device__ __forceinline__ float rb(float f) {
    unsigned int u = __float_as_uint(f);
    u += 0x7FFFu + ((u >> 16) & 1u);
    return __uint_as_float(u & 0xFFFF0000u);
}

// ---------------- prep: one block per (a,j); stage 8 KB, emit frags + Kd ----------------
__global__ __launch_bounds__(256) void ife_prep(const float* __restrict__ kern,
                                                unsigned char* __restrict__ ws)
{
    const int bid = blockIdx.x;           // a*64 + j
    const int a = bid >> 6, j = bid & 63;
    const int t = threadIdx.x;
    __shared__ float st[64][36];          // [f][u], pitch 36 (16B-aligned float4 slots)

    const float* src = kern + ((size_t)j * A_ + a) * (F_ * U_);
    {
        const int f = t >> 2, u0 = (t & 3) * 8;
        *(float4*)&st[f][u0]     = *(const float4*)&src[f * U_ + u0];
        *(float4*)&st[f][u0 + 4] = *(const float4*)&src[f * U_ + u0 + 4];
    }
    __syncthreads();

    unsigned char* dst = ws + (size_t)bid * 8192;
    const int fragid = t >> 6, lane = t & 63, q = lane >> 4, c = lane & 15;

    // K frag (fragid = kc*2 + ut)
    {
        const int kc = fragid >> 1, ut = fragid & 1;
        const int f0 = kc * 32 + q * 8, u = ut * 16 + c;
        unsigned int w[4];
        #pragma unroll
        for (int i = 0; i < 4; ++i)
            w[i] = pk_bf16(st[f0 + 2 * i][u], st[f0 + 2 * i + 1][u]);
        *(uint4*)(dst + fragid * 1024 + lane * 16) = make_uint4(w[0], w[1], w[2], w[3]);
    }
    // W frag (fragid = ft), u-permuted: slots = {4q..4q+3, 16+4q..16+4q+3}
    {
        const int f = fragid * 16 + c;
        const float4 wa = *(const float4*)&st[f][q * 4];        // u = 4q .. 4q+3
        const float4 wb = *(const float4*)&st[f][16 + q * 4];   // u = 16+4q .. 16+4q+3
        unsigned int w[4];
        w[0] = pk_bf16(__expf(2.f * wa.x), __expf(2.f * wa.y));
        w[1] = pk_bf16(__expf(2.f * wa.z), __expf(2.f * wa.w));
        w[2] = pk_bf16(__expf(2.f * wb.x), __expf(2.f * wb.y));
        w[3] = pk_bf16(__expf(2.f * wb.z), __expf(2.f * wb.w));
        *(uint4*)(dst + 4096 + fragid * 1024 + lane * 16) = make_uint4(w[0], w[1], w[2], w[3]);
    }
    // Kd (bf16-rounded so the rank-1 correction exactly cancels the MFMA j-term)
    if (t < U_)
        ((float*)(ws + KD_OFF))[(size_t)bid * U_ + t] = rb(st[j][t]);
}

// ---------------- main: (a, 64-row tile); 8 waves = 2 j-groups x 4 row-waves --------------
// R3-R9: every compiler-mediated overlap was sunk; every wave redundantly loaded the same
// 8 KB/j tile (64 KB/block/j for 8 KB of data). This version stages the two groups' j-tiles
// into LDS ONCE per block per step via async __builtin_amdgcn_global_load_lds (width 16,
// double-buffered, one barrier per step) — the intrinsic has side effects, so the compiler
// cannot sink it; staging latency hides under the previous step's compute. Frag reads
// become ds_read_b128 from LDS. Global frag traffic drops 4x (1.07 GB -> 268 MB).
__global__ __launch_bounds__(512, 4) void ife_main(const float* __restrict__ x,
                                                   const unsigned char* __restrict__ ws,
                                                   float* __restrict__ out)
{
    const int a = blockIdx.y, bt = blockIdx.x, t = threadIdx.x;
    const int wv = t >> 6, lane = t & 63, q = lane >> 4, c = lane & 15;
    const int grp = wv >> 2, w4 = wv & 3;

    // Shared pool: Xf [64][66] (4224 f) + Kd [64][32] (2048 f) = 25.1 KB (SH; later reused
    // as the S-reduction buffer) + frag double-buffer Fbuf[2][2 groups][8192 B] = 32 KB.
    __shared__ __align__(16) float SH[6272];
    __shared__ __align__(16) unsigned char Fbuf[2][2][8192];
    float* Xf = SH;                  // Xf[row][cc] = SH[row*66 + cc]
    float* Kd = SH + 4224;           // Kd[j][u]    = SH[4224 + j*32 + u]

    // X frags (lane holds X[b-row = c][f = kc*32 + q*8 + i]) — B operand of Z^T
    bf16x8 Xh[2];
    {
        const float* xr = x + (size_t)(bt * 64 + w4 * 16 + c) * F_;
        #pragma unroll
        for (int kc = 0; kc < 2; ++kc) {
            const float4 va = *(const float4*)&xr[kc * 32 + q * 8];
            const float4 vb = *(const float4*)&xr[kc * 32 + q * 8 + 4];
            union { unsigned int u[4]; bf16x8 v; } H;
            H.u[0] = pk_bf16(va.x, va.y);
            H.u[1] = pk_bf16(va.z, va.w);
            H.u[2] = pk_bf16(vb.x, vb.y);
            H.u[3] = pk_bf16(vb.z, vb.w);
            Xh[kc] = H.v;
        }
    }
    // Xf (bf16-rounded values, fp32 storage); 512 threads, scalar stores (pitch 66)
    {
        const int row = t >> 3, cb = (t & 7) * 8;
        const float* xsrc = x + (size_t)(bt * 64 + row) * F_ + cb;
        const float4 v0 = *(const float4*)&xsrc[0];
        const float4 v1 = *(const float4*)&xsrc[4];
        float* xd = Xf + row * 66 + cb;
        xd[0] = rb(v0.x); xd[1] = rb(v0.y); xd[2] = rb(v0.z); xd[3] = rb(v0.w);
        xd[4] = rb(v1.x); xd[5] = rb(v1.y); xd[6] = rb(v1.z); xd[7] = rb(v1.w);
    }
    // Kd stage (contiguous 8 KB); 512 threads x 1 float4
    {
        const float* kd = (const float*)(ws + KD_OFF) + (size_t)a * 64 * U_;
        const int jj = t >> 3, u0 = (t & 7) * 4;
        *(float4*)&Kd[jj * 32 + u0] = *(const float4*)&kd[jj * U_ + u0];
    }

    const unsigned char* blob = ws + (size_t)a * 64 * 8192;
    const f32x4 vzero = (f32x4){0.f, 0.f, 0.f, 0.f};

    union { unsigned int u[4]; bf16x8 v; } oc;
    oc.u[0] = 0x3F803F80u; oc.u[1] = 0x3F803F80u; oc.u[2] = 0x3F803F80u; oc.u[3] = 0x3F803F80u;
    const bf16x8 ONES = oc.v;

    f32x4 S0 = vzero, S1 = vzero, S2 = vzero, S3 = vzero;   // S[ft]: score[row=c][f=ft*16+4q+r]

    // async stage of step s into Fbuf[buf]: wave wv covers group tg = wv>>2's tile,
    // frag pair fp = wv&3 (2 KB via two width-16 global_load_lds). LDS dest is
    // wave-uniform base + lane*16 (HW-implicit); global src is per-lane.
    typedef const __attribute__((address_space(1))) unsigned int gau32;
    typedef __attribute__((address_space(3))) unsigned int lau32;
    auto STAGE = [&](int buf, int s) {
        const int tg = wv >> 2, fp = wv & 3;
        const int jt = tg * 32 + s;
        const unsigned char* g = blob + (size_t)jt * 8192 + fp * 2048 + lane * 16;
        unsigned char* l = &Fbuf[buf][tg][fp * 2048];
        __builtin_amdgcn_global_load_lds((gau32*)(g),        (lau32*)(l),        16, 0, 0);
        __builtin_amdgcn_global_load_lds((gau32*)(g + 1024), (lau32*)(l + 1024), 16, 0, 0);
    };

    const int jb = grp * 32;
    const int xfrow = (w4 * 16 + c) * 66;

    STAGE(0, 0);
    __syncthreads();   // staging barrier (Xf/Kd stores + first tile: vmcnt/lgkm drained)

    int cur = 0;
    #pragma unroll 1
    for (int s = 0; s < 32; ++s) {
        if (s < 31) STAGE(cur ^ 1, s + 1);           // async; hides under this step's compute

        const unsigned char* pt = &Fbuf[cur][grp][lane * 16];
        const int j = jb + s;

        // frag reads from LDS (ds_read_b128)
        const bf16x8 K0 = *(const bf16x8*)(pt);
        const bf16x8 K1 = *(const bf16x8*)(pt + 1024);
        const bf16x8 K2 = *(const bf16x8*)(pt + 2048);
        const bf16x8 K3 = *(const bf16x8*)(pt + 3072);

        // per-j scalars: xj for this lane's row; kd for this lane's 8 u-slots
        const float xj = Xf[xfrow + j];
        const f32x4 kda = *(const f32x4*)&Kd[j * 32 + q * 4];        // u = 4q+r
        const f32x4 kdb = *(const f32x4*)&Kd[j * 32 + 16 + q * 4];   // u = 16+4q+r

        // Z^T: lane (q,c) gets Z[u][row=c]: ZA -> u = 4q+r, ZB -> u = 16+4q+r
        f32x4 ZA = vzero, ZB = vzero;
        ZA = __builtin_amdgcn_mfma_f32_16x16x32_bf16(K0, Xh[0], ZA, 0, 0, 0);
        ZA = __builtin_amdgcn_mfma_f32_16x16x32_bf16(K2, Xh[1], ZA, 0, 0, 0);
        ZB = __builtin_amdgcn_mfma_f32_16x16x32_bf16(K1, Xh[0], ZB, 0, 0, 0);
        ZB = __builtin_amdgcn_mfma_f32_16x16x32_bf16(K3, Xh[1], ZB, 0, 0, 0);

        const bf16x8 W0 = *(const bf16x8*)(pt + 4096);
        const bf16x8 W1 = *(const bf16x8*)(pt + 5120);
        const bf16x8 W2 = *(const bf16x8*)(pt + 6144);
        const bf16x8 W3 = *(const bf16x8*)(pt + 7168);

        // rank-1 mask correction + exp; pack to bf16 (E frag, u-permuted slot order)
        union { unsigned int u[4]; bf16x8 v; } E;
        E.u[0] = pk_bf16(__expf(ZA[0] - xj * kda[0]), __expf(ZA[1] - xj * kda[1]));
        E.u[1] = pk_bf16(__expf(ZA[2] - xj * kda[2]), __expf(ZA[3] - xj * kda[3]));
        E.u[2] = pk_bf16(__expf(ZB[0] - xj * kdb[0]), __expf(ZB[1] - xj * kdb[1]));
        E.u[3] = pk_bf16(__expf(ZB[2] - xj * kdb[2]), __expf(ZB[3] - xj * kdb[3]));

        // denominator via MFMA vs ONES A-frag: sv[r] = sum_u E[u][c] (same in all r);
        // sums the bf16-ROUNDED values — matches what PV sums.
        const f32x4 sv = __builtin_amdgcn_mfma_f32_16x16x32_bf16(ONES, E.v, vzero, 0, 0, 0);

        // PV: D[ft] = W[ft] · E (u contraction; both sides share the same u-permutation)
        const f32x4 D0 = __builtin_amdgcn_mfma_f32_16x16x32_bf16(W0, E.v, vzero, 0, 0, 0);
        const f32x4 D1 = __builtin_amdgcn_mfma_f32_16x16x32_bf16(W1, E.v, vzero, 0, 0, 0);
        const f32x4 D2 = __builtin_amdgcn_mfma_f32_16x16x32_bf16(W2, E.v, vzero, 0, 0, 0);
        const f32x4 D3 = __builtin_amdgcn_mfma_f32_16x16x32_bf16(W3, E.v, vzero, 0, 0, 0);

        const float inv = __builtin_amdgcn_rcpf(sv[0]);
        #pragma unroll
        for (int r = 0; r < 4; ++r) {
            S0[r] += D0[r] * inv;
            S1[r] += D1[r] * inv;
            S2[r] += D2[r] * inv;
            S3[r] += D3[r] * inv;
        }

        __syncthreads();   // staging for s+1 complete (vmcnt0) + all reads of cur done
        cur ^= 1;
    }

    // ---- combine the two j-groups' partial S through LDS (overlay on SH, pitch 20) ----
    float* Sred = SH;                           // [w4*64+lane][20] — 5120 floats used
    if (grp == 1) {
        float* pp = Sred + (size_t)(w4 * 64 + lane) * 20;
        *(f32x4*)(pp + 0)  = S0;
        *(f32x4*)(pp + 4)  = S1;
        *(f32x4*)(pp + 8)  = S2;
        *(f32x4*)(pp + 12) = S3;
    }
    __syncthreads();
    if (grp == 0) {
        const float* pp = Sred + (size_t)(w4 * 64 + lane) * 20;
        S0 += *(const f32x4*)(pp + 0);
        S1 += *(const f32x4*)(pp + 4);
        S2 += *(const f32x4*)(pp + 8);
        S3 += *(const f32x4*)(pp + 12);

        // epilogue: mean over j, softmax over f. Lane (q,c) holds row c's f = ft*16+4q+r.
        const float sc = 1.f / 64.f;
        float ex[4][4];
        float part = 0.f;
        #pragma unroll
        for (int r = 0; r < 4; ++r) {
            ex[0][r] = __expf(S0[r] * sc);
            ex[1][r] = __expf(S1[r] * sc);
            ex[2][r] = __expf(S2[r] * sc);
            ex[3][r] = __expf(S3[r] * sc);
            part += ex[0][r] + ex[1][r] + ex[2][r] + ex[3][r];
        }
        part += __shfl_xor(part, 16, 64);
        part += __shfl_xor(part, 32, 64);
        const float inv = 1.f / part;

        const int b = bt * 64 + w4 * 16 + c;
        float* o = out + ((size_t)a * B_ + b) * F_;
        #pragma unroll
        for (int ft = 0; ft < 4; ++ft) {
            float4 v;
            v.x = ex[ft][0] * inv;
            v.y = ex[ft][1] * inv;
            v.z = ex[ft][2] * inv;
            v.w = ex[ft][3] * inv;
            *(float4*)&o[ft * 16 + q * 4] = v;
        }
    }
}

extern "C" void kernel_launch(void* const* d_in, const int* in_sizes, int n_in,
                              void* d_out, int out_size, void* d_ws, size_t ws_size,
                              hipStream_t stream) {
    (void)in_sizes; (void)n_in; (void)out_size; (void)ws_size;
    const float* x    = (const float*)d_in[0];   // [B, F]
    const float* kern = (const float*)d_in[1];   // [F, A, F, U]
    float* out        = (float*)d_out;           // [A, B, F]
    unsigned char* ws = (unsigned char*)d_ws;    // ~4.1 MB used

    hipLaunchKernelGGL(ife_prep, dim3(F_ * A_), dim3(256), 0, stream, kern, ws);
    hipLaunchKernelGGL(ife_main, dim3(B_ / 64, A_), dim3(512), 0, stream, x, ws, out);
}